// Round 9
// baseline (306.618 us; speedup 1.0000x reference)
//
#include <hip/hip_runtime.h>
#include <hip/hip_bf16.h>
#include <stdint.h>

#define G 256
#define NPG 400
#define DEG 32
#define FIN 400
#define H 64
#define NN (G*NPG)        // 102400
#define EE (G*NPG*DEG)    // 3276800
#define EPG (NPG*DEG)     // 12800 edges per graph
#define CPG (EPG+NPG)     // 13200 entries per graph (edges + self loops)
#define NTILE 25          // 16-row dst tiles per graph (25x16 = 400 exactly)
#define ATS 420           // A-tile LDS stride (floats)
#define HTS 72            // h-tile LDS stride (halves)
#define MTSZ 25600        // per-graph M^T elems (64*400)

// wf buffer layout (halves)
#define W1F_OFF 0
#define W1F_N   (13*4*64*8)          // 26624
#define W2F_OFF (W1F_OFF + W1F_N)    // 26624
#define W2F_N   (2*4*64*8)           // 4096
#define W3F_OFF (W2F_OFF + W2F_N)    // 30720
#define WCF_OFF (W3F_OFF + W2F_N)    // 34816
#define WCF_N   (800*4*64*8)         // 1638400
#define WF_TOT  (WCF_OFF + WCF_N)    // 1673216

// kFront block ranges
#define FB_M1   1792                 // 7 per graph * 256
#define FB_NORM (FB_M1 + G)          // 2048
#define FB_WC   (FB_NORM + WCF_N/256) // 2048 + 6400 = 8448

typedef __attribute__((ext_vector_type(8))) _Float16 h8;
typedef __attribute__((ext_vector_type(4))) float f32x4;

static __device__ __forceinline__ unsigned packh2(float a, float b) {
  unsigned short ua = __builtin_bit_cast(unsigned short, (_Float16)a);
  unsigned short ub = __builtin_bit_cast(unsigned short, (_Float16)b);
  return (unsigned)ua | ((unsigned)ub << 16);
}

static __device__ __forceinline__ h8 cvt8(float4 a, float4 b) {
  h8 r;
  r[0] = (_Float16)a.x; r[1] = (_Float16)a.y; r[2] = (_Float16)a.z; r[3] = (_Float16)a.w;
  r[4] = (_Float16)b.x; r[5] = (_Float16)b.y; r[6] = (_Float16)b.z; r[7] = (_Float16)b.w;
  return r;
}

// ---------------- kPackW: W1/W2/W3 -> fp16 B-frag order; zero gbuf ----------
__global__ __launch_bounds__(256) void kPackW(
    const float* __restrict__ W1, const float* __restrict__ W2,
    const float* __restrict__ W3,
    _Float16* __restrict__ wf, float* __restrict__ gbuf)
{
  int idx = blockIdx.x*256 + threadIdx.x;
  if (idx < G*H) gbuf[idx] = 0.f;
  if (idx >= WCF_OFF) return;
  if (idx < W2F_OFF) {                       // W1: [ks 13][nt 4][lane][j]
    int i = idx;
    int j = i & 7, ln = (i >> 3) & 63, nt = (i >> 9) & 3, ks = i >> 11;
    int k = ks*32 + (ln >> 4)*8 + j, col = nt*16 + (ln & 15);
    wf[idx] = (k < FIN) ? (_Float16)W1[k*H + col] : (_Float16)0.f;
  } else if (idx < W3F_OFF) {                // W2: [ks 2][nt 4][lane][j]
    int i = idx - W2F_OFF;
    int j = i & 7, ln = (i >> 3) & 63, nt = (i >> 9) & 3, ks = i >> 11;
    wf[idx] = (_Float16)W2[(ks*32 + (ln >> 4)*8 + j)*H + nt*16 + (ln & 15)];
  } else {                                   // W3
    int i = idx - W3F_OFF;
    int j = i & 7, ln = (i >> 3) & 63, nt = (i >> 9) & 3, ks = i >> 11;
    wf[idx] = (_Float16)W3[(ks*32 + (ln >> 4)*8 + j)*H + nt*16 + (ln & 15)];
  }
}

// ---------------- kFront: fused kM1 | kNorm | Wc-pack (independent roles) ----
__global__ __launch_bounds__(256) void kFront(
    const float* __restrict__ x, const int* __restrict__ ei,
    const float* __restrict__ ew, const float* __restrict__ Wc,
    const _Float16* __restrict__ wfr, _Float16* __restrict__ wfw,
    uint2* __restrict__ ent, uint32_t* __restrict__ boff,
    _Float16* __restrict__ mt1)
{
  extern __shared__ char smem[];
  const int b = blockIdx.x, tid = threadIdx.x;

  if (b < FB_M1) {
    // ---- kM1 role: MT1[g][feat][node] = (x @ W1)^T, fp16 ----
    _Float16* sh = (_Float16*)smem;            // 64*HTS halves
    const int lane = tid & 63, wave = tid >> 6;
    const int l15 = lane & 15, kgrp = lane >> 4;
    const int g = b / 7, bt = b % 7;           // nodes bt*64..+63
    const int node_l = bt*64 + wave*16 + l15;
    const int arow = (node_l < NPG) ? node_l : NPG-1;
    const float* xp = x + ((size_t)g*NPG + arow)*FIN;

    h8 af[13];
    #pragma unroll
    for (int ks = 0; ks < 13; ++ks) {
      int kb = ks*32 + kgrp*8;
      if (kb + 8 <= FIN) {
        float4 a0 = *(const float4*)(xp + kb);
        float4 a1 = *(const float4*)(xp + kb + 4);
        af[ks] = cvt8(a0, a1);
      } else {
        h8 z;
        #pragma unroll
        for (int j = 0; j < 8; ++j) z[j] = (_Float16)0.f;
        af[ks] = z;
      }
    }
    f32x4 acc[4] = {{0,0,0,0},{0,0,0,0},{0,0,0,0},{0,0,0,0}};
    for (int nt = 0; nt < 4; ++nt)
      for (int ks = 0; ks < 13; ++ks) {
        h8 bf = *(const h8*)&wfr[W1F_OFF + (((size_t)ks*4 + nt)*64 + lane)*8];
        acc[nt] = __builtin_amdgcn_mfma_f32_16x16x32_f16(af[ks], bf, acc[nt], 0, 0, 0);
      }
    #pragma unroll
    for (int nt = 0; nt < 4; ++nt) {
      int feat = nt*16 + l15;
      #pragma unroll
      for (int r = 0; r < 4; ++r)
        sh[(wave*16 + kgrp*4 + r)*HTS + feat] = (_Float16)acc[nt][r];
    }
    __syncthreads();
    const unsigned short* shu = (const unsigned short*)sh;
    for (int i = tid; i < 64*16; i += 256) {
      int feat = i >> 4, seg = i & 15;
      int nl = seg*4, gn = bt*64 + nl;
      if (gn < NPG) {
        uint2 u;
        u.x = (unsigned)shu[(nl+0)*HTS + feat] | ((unsigned)shu[(nl+1)*HTS + feat] << 16);
        u.y = (unsigned)shu[(nl+2)*HTS + feat] | ((unsigned)shu[(nl+3)*HTS + feat] << 16);
        *(uint2*)&mt1[(size_t)g*MTSZ + feat*400 + gn] = u;
      }
    }
  } else if (b < FB_NORM) {
    // ---- kNorm role: degree + normalized entries bucketed by 16-row tile ----
    float* deg = (float*)smem;                 // 400
    float* dv  = deg + NPG;                    // 400
    uint32_t* bcnt = (uint32_t*)(dv + NPG);    // 32
    uint32_t* bpos = bcnt + 32;                // 32
    const int g = b - FB_M1;
    const int ebase = g*EPG, nbase = g*NPG;
    const int* rowp = ei;
    const int* colp = ei + EE;
    if (tid < NTILE) bcnt[tid] = 0u;
    for (int v = tid; v < NPG; v += 256) deg[v] = 1.0f;
    __syncthreads();
    for (int e = tid; e < EPG; e += 256) {
      int c = colp[ebase+e] - nbase;
      atomicAdd(&deg[c], ew[ebase+e]);
      atomicAdd(&bcnt[c >> 4], 1u);
    }
    __syncthreads();
    for (int v = tid; v < NPG; v += 256) dv[v] = rsqrtf(deg[v]);
    if (tid == 0) {
      uint32_t s = 0;
      #pragma unroll
      for (int t = 0; t < NTILE; ++t) {
        uint32_t c = bcnt[t] + 16u;            // + 16 self loops per tile
        bcnt[t] = s; bpos[t] = s; s += c;
      }
    }
    __syncthreads();
    if (tid < NTILE) boff[g*32 + tid] = bcnt[tid];
    if (tid == NTILE) boff[g*32 + NTILE] = (uint32_t)CPG;
    uint2* eb = ent + (size_t)g*CPG;
    for (int e = tid; e < EPG; e += 256) {
      int src = rowp[ebase+e] - nbase;
      int dst = colp[ebase+e] - nbase;
      float nm = dv[src] * ew[ebase+e] * dv[dst];
      uint32_t p = atomicAdd(&bpos[dst >> 4], 1u);
      eb[p] = make_uint2(((unsigned)dst << 16) | (unsigned)src, __float_as_uint(nm));
    }
    for (int v = tid; v < NPG; v += 256) {
      uint32_t p = atomicAdd(&bpos[v >> 4], 1u);
      eb[p] = make_uint2(((unsigned)v << 16) | (unsigned)v, __float_as_uint(dv[v]*dv[v]));
    }
  } else {
    // ---- Wc-pack role: wf[WCF_OFF + idx], k' = feat*400 + node perm ----
    int idx = (b - FB_NORM)*256 + tid;         // < 1638400
    int j = idx & 7, ln = (idx >> 3) & 63, nt = (idx >> 9) & 3, kt = idx >> 11;
    int kp = kt*32 + (ln >> 4)*8 + j;
    int node = kp % 400, feat = kp / 400;
    int col = nt*16 + (ln & 15);
    wfw[WCF_OFF + idx] = (_Float16)Wc[((size_t)node*64 + feat)*64 + col];
  }
}

// ---------------- kAgg<WMUL>: one 16-row dst tile: scatter + agg MFMA --------
// WMUL=1: + bias + relu + fused next-layer GEMM -> MT_out.  WMUL=0: + bias -> MT out.
template<int WMUL>
__global__ __launch_bounds__(256, 4) void kAgg(
    const _Float16* __restrict__ mtin, const _Float16* __restrict__ wfn,
    const float* __restrict__ bias,
    const uint2* __restrict__ ent, const uint32_t* __restrict__ boff,
    _Float16* __restrict__ out)
{
  extern __shared__ char smem[];
  float* sAT = (float*)smem;                     // 16*420*4 = 26880 B
  _Float16* sh = (_Float16*)(smem + 16*ATS*4);   // 16*72*2  = 2304 B
  const int tid = threadIdx.x, lane = tid & 63;
  const int l15 = lane & 15, kgrp = lane >> 4;
  const int bid = blockIdx.x;
  const int g = bid & 255, t = bid >> 8;         // same-graph blocks share XCD
  const int t0 = t*16;
  const int nt = tid >> 6;                       // wave = output col quarter
  const uint2* eb = ent + (size_t)g*CPG;
  const uint32_t s0 = boff[g*32 + t], s1 = boff[g*32 + t + 1];

  // global prefetches (independent; overlap with zeroing)
  h8 BF[13];
  const _Float16* mrow = mtin + (size_t)g*MTSZ + (nt*16 + l15)*400;
  #pragma unroll
  for (int ks = 0; ks < 13; ++ks)
    BF[ks] = *(const h8*)(mrow + ks*32 + kgrp*8);
  const float bv = bias[nt*16 + l15];
  h8 WF2[2];
  if (WMUL) {
    WF2[0] = *(const h8*)&wfn[((size_t)(0*4 + nt)*64 + lane)*8];
    WF2[1] = *(const h8*)&wfn[((size_t)(1*4 + nt)*64 + lane)*8];
  }
  const uint32_t e0 = s0 + tid;
  uint2 E0 = make_uint2(0,0), E1 = make_uint2(0,0), E2 = make_uint2(0,0);
  if (e0       < s1) E0 = eb[e0];
  if (e0 + 256 < s1) E1 = eb[e0 + 256];
  if (e0 + 512 < s1) E2 = eb[e0 + 512];

  // zero A-tile
  { float4* p = (float4*)sAT;
    for (int i = tid; i < 16*ATS/4; i += 256) p[i] = make_float4(0,0,0,0); }
  __syncthreads();

  // scatter
  if (e0       < s1) atomicAdd(&sAT[((int)(E0.x >> 16) - t0)*ATS + (int)(E0.x & 0xffffu)], __uint_as_float(E0.y));
  if (e0 + 256 < s1) atomicAdd(&sAT[((int)(E1.x >> 16) - t0)*ATS + (int)(E1.x & 0xffffu)], __uint_as_float(E1.y));
  if (e0 + 512 < s1) atomicAdd(&sAT[((int)(E2.x >> 16) - t0)*ATS + (int)(E2.x & 0xffffu)], __uint_as_float(E2.y));
  for (uint32_t e = e0 + 768; e < s1; e += 256) {      // overflow guard
    uint2 E = eb[e];
    atomicAdd(&sAT[((int)(E.x >> 16) - t0)*ATS + (int)(E.x & 0xffffu)], __uint_as_float(E.y));
  }
  __syncthreads();

  // agg MFMA: 16 nodes x 16 cols per wave
  f32x4 acc = {0,0,0,0};
  const float* ap = &sAT[l15*ATS];
  #pragma unroll
  for (int ks = 0; ks < 13; ++ks) {
    int kb = ks*32 + kgrp*8;
    float4 a0 = *(const float4*)(ap + kb);
    float4 a1 = *(const float4*)(ap + kb + 4);
    acc = __builtin_amdgcn_mfma_f32_16x16x32_f16(cvt8(a0, a1), BF[ks], acc, 0, 0, 0);
  }

  const int node0 = t0 + kgrp*4;
  if (!WMUL) {
    // layer 3: bias only, store MT layout (= h3 transposed k' order)
    uint2 u;
    u.x = packh2(acc[0] + bv, acc[1] + bv);
    u.y = packh2(acc[2] + bv, acc[3] + bv);
    *(uint2*)&out[(size_t)g*MTSZ + (nt*16 + l15)*400 + node0] = u;
  } else {
    // bias + relu -> h-tile LDS
    #pragma unroll
    for (int r = 0; r < 4; ++r)
      sh[(kgrp*4 + r)*HTS + nt*16 + l15] = (_Float16)fmaxf(acc[r] + bv, 0.f);
    __syncthreads();
    // fused next-layer GEMM: M_out-tile = h_tile @ Wn
    f32x4 acc2 = {0,0,0,0};
    const _Float16* hp = &sh[l15*HTS];
    acc2 = __builtin_amdgcn_mfma_f32_16x16x32_f16(*(const h8*)(hp + kgrp*8),      WF2[0], acc2, 0, 0, 0);
    acc2 = __builtin_amdgcn_mfma_f32_16x16x32_f16(*(const h8*)(hp + 32 + kgrp*8), WF2[1], acc2, 0, 0, 0);
    uint2 u;
    u.x = packh2(acc2[0], acc2[1]);
    u.y = packh2(acc2[2], acc2[3]);
    *(uint2*)&out[(size_t)g*MTSZ + (nt*16 + l15)*400 + node0] = u;
  }
}

// ---------------- kRead: gbuf += h3T[16 graphs] @ Wc' (split-K, MFMA) --------
__global__ __launch_bounds__(256) void kRead(
    const _Float16* __restrict__ h3, const _Float16* __restrict__ wfc,
    float* __restrict__ gbuf)
{
  const int tid = threadIdx.x, lane = tid & 63, nt = tid >> 6;
  const int l15 = lane & 15, kgrp = lane >> 4;
  const int rt = blockIdx.x & 15, kc = blockIdx.x >> 4;   // 16 row-tiles x 32 k-chunks
  f32x4 acc = {0,0,0,0};
  const _Float16* hp = h3 + (size_t)(rt*16 + l15)*MTSZ;
  for (int ks = 0; ks < 25; ++ks) {
    int kt = kc*25 + ks;
    h8 af = *(const h8*)(hp + kt*32 + kgrp*8);
    h8 bf = *(const h8*)(wfc + (((size_t)kt*4 + nt)*64 + lane)*8);
    acc = __builtin_amdgcn_mfma_f32_16x16x32_f16(af, bf, acc, 0, 0, 0);
  }
  #pragma unroll
  for (int r = 0; r < 4; ++r)
    atomicAdd(&gbuf[(size_t)(rt*16 + kgrp*4 + r)*H + nt*16 + l15], acc[r]);
}

// ---------------- k6: out = (g + bc) @ Wl + bl ----------------
__global__ __launch_bounds__(64) void k6_final(
    const float* __restrict__ gbuf, const float* __restrict__ bc,
    const float* __restrict__ Wl, const float* __restrict__ bl,
    float* __restrict__ out)
{
  int t = blockIdx.x*64 + threadIdx.x;   // 512 = 256 graphs * 2 outputs
  int gr = t >> 1, c = t & 1;
  float acc = bl[c];
  for (int f = 0; f < H; ++f)
    acc += (gbuf[gr*H + f] + bc[f]) * Wl[f*2 + c];
  out[gr*2 + c] = acc;
}

extern "C" void kernel_launch(void* const* d_in, const int* in_sizes, int n_in,
                              void* d_out, int out_size, void* d_ws, size_t ws_size,
                              hipStream_t stream)
{
  const float* x  = (const float*)d_in[0];
  const int*   ei = (const int*)d_in[1];
  const float* ew = (const float*)d_in[2];
  const float* W1 = (const float*)d_in[3];
  const float* b1 = (const float*)d_in[4];
  const float* W2 = (const float*)d_in[5];
  const float* b2 = (const float*)d_in[6];
  const float* W3 = (const float*)d_in[7];
  const float* b3 = (const float*)d_in[8];
  const float* Wc = (const float*)d_in[9];
  const float* bc = (const float*)d_in[10];
  const float* Wl = (const float*)d_in[11];
  const float* bl = (const float*)d_in[12];
  float* out = (float*)d_out;
  (void)ws_size;

  char* ws = (char*)d_ws;
  size_t o = 0;
  uint2*     ent  = (uint2*)(ws + o);     o += (size_t)G*CPG*8;        // 27.0 MB
  uint32_t*  boff = (uint32_t*)(ws + o);  o += (size_t)G*32*4;         // 32 KB
  _Float16*  mtA  = (_Float16*)(ws + o);  o += (size_t)G*MTSZ*2 + 256; // 13.1 MB
  _Float16*  mtB  = (_Float16*)(ws + o);  o += (size_t)G*MTSZ*2 + 256; // 13.1 MB
  _Float16*  wf   = (_Float16*)(ws + o);  o += (size_t)WF_TOT*2;       // 3.3 MB
  float*     gbuf = (float*)(ws + o);     o += (size_t)G*H*4;          // 64 KB

  kPackW<<<(WCF_OFF+255)/256, 256, 0, stream>>>(W1, W2, W3, wf, gbuf);
  kFront<<<FB_WC, 256, 64*HTS*2, stream>>>(x, ei, ew, Wc, wf, wf, ent, boff, mtA);
  const int aggLds = 16*ATS*4 + 16*HTS*2;   // 26880 + 2304 = 29184 B
  kAgg<1><<<NTILE*G, 256, aggLds, stream>>>(mtA, wf + W2F_OFF, b1, ent, boff, mtB);
  kAgg<1><<<NTILE*G, 256, aggLds, stream>>>(mtB, wf + W3F_OFF, b2, ent, boff, mtA);
  kAgg<0><<<NTILE*G, 256, aggLds, stream>>>(mtA, wf, b3, ent, boff, mtB);
  kRead<<<512, 256, 0, stream>>>(mtB, wf + WCF_OFF, gbuf);
  k6_final<<<8, 64, 0, stream>>>(gbuf, bc, Wl, bl, out);
}

// Round 10
// 271.621 us; speedup vs baseline: 1.1288x; 1.1288x over previous
//
#include <hip/hip_runtime.h>
#include <hip/hip_bf16.h>
#include <stdint.h>

#define G 256
#define NPG 400
#define DEG 32
#define FIN 400
#define H 64
#define NN (G*NPG)        // 102400
#define EE (G*NPG*DEG)    // 3276800
#define EPG (NPG*DEG)     // 12800 edges per graph
#define CPG (EPG+NPG)     // 13200 entries per graph (edges + self loops)
#define NTILE 25          // 16-row dst tiles per graph (25x16 = 400 exactly)
#define ATS 420           // A-tile LDS stride (floats)
#define HTS 72            // h-tile LDS stride (halves)
#define MTSZ 25600        // per-graph M^T elems (64*400)

// wf buffer layout (halves)
#define W1F_OFF 0
#define W1F_N   (13*4*64*8)          // 26624
#define W2F_OFF (W1F_OFF + W1F_N)    // 26624
#define W2F_N   (2*4*64*8)           // 4096
#define W3F_OFF (W2F_OFF + W2F_N)    // 30720
#define WCF_OFF (W3F_OFF + W2F_N)    // 34816
#define WCF_N   (800*4*64*8)         // 1638400

typedef __attribute__((ext_vector_type(8))) _Float16 h8;
typedef __attribute__((ext_vector_type(4))) float f32x4;

static __device__ __forceinline__ unsigned packh2(float a, float b) {
  unsigned short ua = __builtin_bit_cast(unsigned short, (_Float16)a);
  unsigned short ub = __builtin_bit_cast(unsigned short, (_Float16)b);
  return (unsigned)ua | ((unsigned)ub << 16);
}

static __device__ __forceinline__ h8 cvt8(float4 a, float4 b) {
  h8 r;
  r[0] = (_Float16)a.x; r[1] = (_Float16)a.y; r[2] = (_Float16)a.z; r[3] = (_Float16)a.w;
  r[4] = (_Float16)b.x; r[5] = (_Float16)b.y; r[6] = (_Float16)b.z; r[7] = (_Float16)b.w;
  return r;
}

// ---------------- kPackW: W1/W2/W3 -> fp16 B-frag order; zero gbuf ----------
__global__ __launch_bounds__(256) void kPackW(
    const float* __restrict__ W1, const float* __restrict__ W2,
    const float* __restrict__ W3,
    _Float16* __restrict__ wf, float* __restrict__ gbuf)
{
  int idx = blockIdx.x*256 + threadIdx.x;
  if (idx < G*H) gbuf[idx] = 0.f;
  if (idx >= WCF_OFF) return;
  if (idx < W2F_OFF) {                       // W1: [ks 13][nt 4][lane][j]
    int i = idx;
    int j = i & 7, ln = (i >> 3) & 63, nt = (i >> 9) & 3, ks = i >> 11;
    int k = ks*32 + (ln >> 4)*8 + j, col = nt*16 + (ln & 15);
    wf[idx] = (k < FIN) ? (_Float16)W1[k*H + col] : (_Float16)0.f;
  } else if (idx < W3F_OFF) {                // W2: [ks 2][nt 4][lane][j]
    int i = idx - W2F_OFF;
    int j = i & 7, ln = (i >> 3) & 63, nt = (i >> 9) & 3, ks = i >> 11;
    wf[idx] = (_Float16)W2[(ks*32 + (ln >> 4)*8 + j)*H + nt*16 + (ln & 15)];
  } else {                                   // W3
    int i = idx - W3F_OFF;
    int j = i & 7, ln = (i >> 3) & 63, nt = (i >> 9) & 3, ks = i >> 11;
    wf[idx] = (_Float16)W3[(ks*32 + (ln >> 4)*8 + j)*H + nt*16 + (ln & 15)];
  }
}

// ---------------- kWcPack: Wc -> fp16 frag order with k' = feat*400+node ----
__global__ __launch_bounds__(256) void kWcPack(
    const float* __restrict__ Wc, _Float16* __restrict__ wf)
{
  int idx = blockIdx.x*256 + threadIdx.x;      // < WCF_N
  int j = idx & 7, ln = (idx >> 3) & 63, nt = (idx >> 9) & 3, kt = idx >> 11;
  int kp = kt*32 + (ln >> 4)*8 + j;            // 0..25599
  int node = kp % 400, feat = kp / 400;
  int col = nt*16 + (ln & 15);
  wf[WCF_OFF + idx] = (_Float16)Wc[((size_t)node*64 + feat)*64 + col];
}

// ---------------- kNorm: 1024 thr; degree + entries bucketed by 16-row tile --
__global__ __launch_bounds__(1024) void kNorm(
    const int* __restrict__ ei, const float* __restrict__ ew,
    uint2* __restrict__ ent, uint32_t* __restrict__ boff)
{
  __shared__ float deg[NPG];
  __shared__ float dv[NPG];
  __shared__ uint32_t bcnt[32], bpos[32];
  const int g = blockIdx.x, tid = threadIdx.x;
  const int ebase = g*EPG, nbase = g*NPG;
  const int* rowp = ei;          // sources
  const int* colp = ei + EE;     // targets
  if (tid < NTILE) bcnt[tid] = 0u;
  for (int v = tid; v < NPG; v += 1024) deg[v] = 1.0f;   // self-loop weight
  __syncthreads();
  for (int e = tid; e < EPG; e += 1024) {
    int c = colp[ebase+e] - nbase;
    atomicAdd(&deg[c], ew[ebase+e]);
    atomicAdd(&bcnt[c >> 4], 1u);
  }
  __syncthreads();
  for (int v = tid; v < NPG; v += 1024) dv[v] = rsqrtf(deg[v]);
  if (tid == 0) {
    uint32_t s = 0;
    #pragma unroll
    for (int t = 0; t < NTILE; ++t) {
      uint32_t c = bcnt[t] + 16u;              // + 16 self loops per tile
      bcnt[t] = s; bpos[t] = s; s += c;
    }
  }
  __syncthreads();
  if (tid < NTILE) boff[g*32 + tid] = bcnt[tid];
  if (tid == NTILE) boff[g*32 + NTILE] = (uint32_t)CPG;
  uint2* eb = ent + (size_t)g*CPG;
  for (int e = tid; e < EPG; e += 1024) {
    int src = rowp[ebase+e] - nbase;
    int dst = colp[ebase+e] - nbase;
    float nm = dv[src] * ew[ebase+e] * dv[dst];
    uint32_t p = atomicAdd(&bpos[dst >> 4], 1u);
    eb[p] = make_uint2(((unsigned)dst << 16) | (unsigned)src, __float_as_uint(nm));
  }
  for (int v = tid; v < NPG; v += 1024) {
    uint32_t p = atomicAdd(&bpos[v >> 4], 1u);
    eb[p] = make_uint2(((unsigned)v << 16) | (unsigned)v, __float_as_uint(dv[v]*dv[v]));
  }
}

// ---------------- kM1: MT1 = (x @ W1)^T  per-graph [feat][node], fp16 -------
__global__ __launch_bounds__(256, 4) void kM1(
    const float* __restrict__ x, const _Float16* __restrict__ wf,
    _Float16* __restrict__ mt1)
{
  __shared__ _Float16 sh[64*HTS];            // 9216 B out-stage
  const int tid = threadIdx.x, lane = tid & 63, wave = tid >> 6;
  const int l15 = lane & 15, kgrp = lane >> 4;
  const int g = blockIdx.y, b = blockIdx.x;  // b < 7, nodes b*64..b*64+63
  const int node_l = b*64 + wave*16 + l15;
  const int arow = (node_l < NPG) ? node_l : NPG-1;
  const float* xp = x + ((size_t)g*NPG + arow)*FIN;

  h8 af[13];
  #pragma unroll
  for (int ks = 0; ks < 13; ++ks) {
    int kb = ks*32 + kgrp*8;
    if (kb + 8 <= FIN) {
      float4 a0 = *(const float4*)(xp + kb);
      float4 a1 = *(const float4*)(xp + kb + 4);
      af[ks] = cvt8(a0, a1);
    } else {
      h8 z;
      #pragma unroll
      for (int j = 0; j < 8; ++j) z[j] = (_Float16)0.f;
      af[ks] = z;
    }
  }
  f32x4 acc[4] = {{0,0,0,0},{0,0,0,0},{0,0,0,0},{0,0,0,0}};
  for (int nt = 0; nt < 4; ++nt)
    for (int ks = 0; ks < 13; ++ks) {
      h8 bf = *(const h8*)&wf[W1F_OFF + (((size_t)ks*4 + nt)*64 + lane)*8];
      acc[nt] = __builtin_amdgcn_mfma_f32_16x16x32_f16(af[ks], bf, acc[nt], 0, 0, 0);
    }
  // stage [node_local][feat]
  #pragma unroll
  for (int nt = 0; nt < 4; ++nt) {
    int feat = nt*16 + l15;
    #pragma unroll
    for (int r = 0; r < 4; ++r)
      sh[(wave*16 + kgrp*4 + r)*HTS + feat] = (_Float16)acc[nt][r];
  }
  __syncthreads();
  // transposed coalesced store: MT1[g][feat][b*64 + 0..63]
  const unsigned short* shu = (const unsigned short*)sh;
  for (int i = tid; i < 64*16; i += 256) {
    int feat = i >> 4, seg = i & 15;
    int nl = seg*4, gn = b*64 + nl;
    if (gn < NPG) {
      uint2 u;
      u.x = (unsigned)shu[(nl+0)*HTS + feat] | ((unsigned)shu[(nl+1)*HTS + feat] << 16);
      u.y = (unsigned)shu[(nl+2)*HTS + feat] | ((unsigned)shu[(nl+3)*HTS + feat] << 16);
      *(uint2*)&mt1[(size_t)g*MTSZ + feat*400 + gn] = u;
    }
  }
}

// ---------------- kAgg<WMUL>: one 16-row dst tile: scatter + agg MFMA --------
// WMUL=1: + bias + relu + fused next-layer GEMM -> MT_out.  WMUL=0: + bias -> MT out.
template<int WMUL>
__global__ __launch_bounds__(256, 4) void kAgg(
    const _Float16* __restrict__ mtin, const _Float16* __restrict__ wfn,
    const float* __restrict__ bias,
    const uint2* __restrict__ ent, const uint32_t* __restrict__ boff,
    _Float16* __restrict__ out)
{
  extern __shared__ char smem[];
  float* sAT = (float*)smem;                     // 16*420*4 = 26880 B
  _Float16* sh = (_Float16*)(smem + 16*ATS*4);   // 16*72*2  = 2304 B
  const int tid = threadIdx.x, lane = tid & 63;
  const int l15 = lane & 15, kgrp = lane >> 4;
  const int bid = blockIdx.x;
  const int g = bid & 255, t = bid >> 8;         // same-graph blocks share XCD
  const int t0 = t*16;
  const int nt = tid >> 6;                       // wave = output col quarter
  const uint2* eb = ent + (size_t)g*CPG;
  const uint32_t s0 = boff[g*32 + t], s1 = boff[g*32 + t + 1];

  // global prefetches (independent; overlap with zeroing)
  h8 BF[13];
  const _Float16* mrow = mtin + (size_t)g*MTSZ + (nt*16 + l15)*400;
  #pragma unroll
  for (int ks = 0; ks < 13; ++ks)
    BF[ks] = *(const h8*)(mrow + ks*32 + kgrp*8);
  const float bv = bias[nt*16 + l15];
  h8 WF2[2];
  if (WMUL) {
    WF2[0] = *(const h8*)&wfn[((size_t)(0*4 + nt)*64 + lane)*8];
    WF2[1] = *(const h8*)&wfn[((size_t)(1*4 + nt)*64 + lane)*8];
  }
  const uint32_t e0 = s0 + tid;
  uint2 E0 = make_uint2(0,0), E1 = make_uint2(0,0), E2 = make_uint2(0,0);
  if (e0       < s1) E0 = eb[e0];
  if (e0 + 256 < s1) E1 = eb[e0 + 256];
  if (e0 + 512 < s1) E2 = eb[e0 + 512];

  // zero A-tile
  { float4* p = (float4*)sAT;
    for (int i = tid; i < 16*ATS/4; i += 256) p[i] = make_float4(0,0,0,0); }
  __syncthreads();

  // scatter
  if (e0       < s1) atomicAdd(&sAT[((int)(E0.x >> 16) - t0)*ATS + (int)(E0.x & 0xffffu)], __uint_as_float(E0.y));
  if (e0 + 256 < s1) atomicAdd(&sAT[((int)(E1.x >> 16) - t0)*ATS + (int)(E1.x & 0xffffu)], __uint_as_float(E1.y));
  if (e0 + 512 < s1) atomicAdd(&sAT[((int)(E2.x >> 16) - t0)*ATS + (int)(E2.x & 0xffffu)], __uint_as_float(E2.y));
  for (uint32_t e = e0 + 768; e < s1; e += 256) {      // overflow guard
    uint2 E = eb[e];
    atomicAdd(&sAT[((int)(E.x >> 16) - t0)*ATS + (int)(E.x & 0xffffu)], __uint_as_float(E.y));
  }
  __syncthreads();

  // agg MFMA: 16 nodes x 16 cols per wave
  f32x4 acc = {0,0,0,0};
  const float* ap = &sAT[l15*ATS];
  #pragma unroll
  for (int ks = 0; ks < 13; ++ks) {
    int kb = ks*32 + kgrp*8;
    float4 a0 = *(const float4*)(ap + kb);
    float4 a1 = *(const float4*)(ap + kb + 4);
    acc = __builtin_amdgcn_mfma_f32_16x16x32_f16(cvt8(a0, a1), BF[ks], acc, 0, 0, 0);
  }

  const int node0 = t0 + kgrp*4;
  if (!WMUL) {
    // layer 3: bias only, store MT layout (= h3 transposed k' order)
    uint2 u;
    u.x = packh2(acc[0] + bv, acc[1] + bv);
    u.y = packh2(acc[2] + bv, acc[3] + bv);
    *(uint2*)&out[(size_t)g*MTSZ + (nt*16 + l15)*400 + node0] = u;
  } else {
    // bias + relu -> h-tile LDS
    #pragma unroll
    for (int r = 0; r < 4; ++r)
      sh[(kgrp*4 + r)*HTS + nt*16 + l15] = (_Float16)fmaxf(acc[r] + bv, 0.f);
    __syncthreads();
    // fused next-layer GEMM: M_out-tile = h_tile @ Wn
    f32x4 acc2 = {0,0,0,0};
    const _Float16* hp = &sh[l15*HTS];
    acc2 = __builtin_amdgcn_mfma_f32_16x16x32_f16(*(const h8*)(hp + kgrp*8),      WF2[0], acc2, 0, 0, 0);
    acc2 = __builtin_amdgcn_mfma_f32_16x16x32_f16(*(const h8*)(hp + 32 + kgrp*8), WF2[1], acc2, 0, 0, 0);
    uint2 u;
    u.x = packh2(acc2[0], acc2[1]);
    u.y = packh2(acc2[2], acc2[3]);
    *(uint2*)&out[(size_t)g*MTSZ + (nt*16 + l15)*400 + node0] = u;
  }
}

// ---------------- kRead: gbuf += h3T[16 graphs] @ Wc' (split-K, MFMA) --------
__global__ __launch_bounds__(256) void kRead(
    const _Float16* __restrict__ h3, const _Float16* __restrict__ wfc,
    float* __restrict__ gbuf)
{
  const int tid = threadIdx.x, lane = tid & 63, nt = tid >> 6;
  const int l15 = lane & 15, kgrp = lane >> 4;
  const int rt = blockIdx.x & 15, kc = blockIdx.x >> 4;   // 16 row-tiles x 32 k-chunks
  f32x4 acc = {0,0,0,0};
  const _Float16* hp = h3 + (size_t)(rt*16 + l15)*MTSZ;
  for (int ks = 0; ks < 25; ++ks) {
    int kt = kc*25 + ks;
    h8 af = *(const h8*)(hp + kt*32 + kgrp*8);
    h8 bf = *(const h8*)(wfc + (((size_t)kt*4 + nt)*64 + lane)*8);
    acc = __builtin_amdgcn_mfma_f32_16x16x32_f16(af, bf, acc, 0, 0, 0);
  }
  #pragma unroll
  for (int r = 0; r < 4; ++r)
    atomicAdd(&gbuf[(size_t)(rt*16 + kgrp*4 + r)*H + nt*16 + l15], acc[r]);
}

// ---------------- k6: out = (g + bc) @ Wl + bl ----------------
__global__ __launch_bounds__(64) void k6_final(
    const float* __restrict__ gbuf, const float* __restrict__ bc,
    const float* __restrict__ Wl, const float* __restrict__ bl,
    float* __restrict__ out)
{
  int t = blockIdx.x*64 + threadIdx.x;   // 512 = 256 graphs * 2 outputs
  int gr = t >> 1, c = t & 1;
  float acc = bl[c];
  for (int f = 0; f < H; ++f)
    acc += (gbuf[gr*H + f] + bc[f]) * Wl[f*2 + c];
  out[gr*2 + c] = acc;
}

extern "C" void kernel_launch(void* const* d_in, const int* in_sizes, int n_in,
                              void* d_out, int out_size, void* d_ws, size_t ws_size,
                              hipStream_t stream)
{
  const float* x  = (const float*)d_in[0];
  const int*   ei = (const int*)d_in[1];
  const float* ew = (const float*)d_in[2];
  const float* W1 = (const float*)d_in[3];
  const float* b1 = (const float*)d_in[4];
  const float* W2 = (const float*)d_in[5];
  const float* b2 = (const float*)d_in[6];
  const float* W3 = (const float*)d_in[7];
  const float* b3 = (const float*)d_in[8];
  const float* Wc = (const float*)d_in[9];
  const float* bc = (const float*)d_in[10];
  const float* Wl = (const float*)d_in[11];
  const float* bl = (const float*)d_in[12];
  float* out = (float*)d_out;
  (void)ws_size;

  char* ws = (char*)d_ws;
  size_t o = 0;
  uint2*     ent  = (uint2*)(ws + o);     o += (size_t)G*CPG*8;        // 27.0 MB
  uint32_t*  boff = (uint32_t*)(ws + o);  o += (size_t)G*32*4;         // 32 KB
  _Float16*  mtA  = (_Float16*)(ws + o);  o += (size_t)G*MTSZ*2 + 256; // 13.1 MB
  _Float16*  mtB  = (_Float16*)(ws + o);  o += (size_t)G*MTSZ*2 + 256; // 13.1 MB
  _Float16*  wf   = (_Float16*)(ws + o);  o += (size_t)(WCF_OFF+WCF_N)*2; // 3.3 MB
  float*     gbuf = (float*)(ws + o);     o += (size_t)G*H*4;          // 64 KB

  kPackW<<<(WCF_OFF+255)/256, 256, 0, stream>>>(W1, W2, W3, wf, gbuf);
  kNorm<<<G, 1024, 0, stream>>>(ei, ew, ent, boff);
  kM1<<<dim3(7, G), 256, 0, stream>>>(x, wf, mtA);
  const int aggLds = 16*ATS*4 + 16*HTS*2;   // 26880 + 2304 = 29184 B
  kAgg<1><<<NTILE*G, 256, aggLds, stream>>>(mtA, wf + W2F_OFF, b1, ent, boff, mtB);
  kAgg<1><<<NTILE*G, 256, aggLds, stream>>>(mtB, wf + W3F_OFF, b2, ent, boff, mtA);
  kWcPack<<<WCF_N/256, 256, 0, stream>>>(Wc, wf);
  kAgg<0><<<NTILE*G, 256, aggLds, stream>>>(mtA, wf, b3, ent, boff, mtB);
  kRead<<<512, 256, 0, stream>>>(mtB, wf + WCF_OFF, gbuf);
  k6_final<<<8, 64, 0, stream>>>(gbuf, bc, Wl, bl, out);
}

// Round 11
// 267.718 us; speedup vs baseline: 1.1453x; 1.0146x over previous
//
#include <hip/hip_runtime.h>
#include <hip/hip_bf16.h>
#include <stdint.h>

#define G 256
#define NPG 400
#define DEG 32
#define FIN 400
#define H 64
#define NN (G*NPG)        // 102400
#define EE (G*NPG*DEG)    // 3276800
#define EPG (NPG*DEG)     // 12800 edges per graph
#define CPG (EPG+NPG)     // 13200 entries per graph (edges + self loops)
#define NTILE 25          // 16-row dst tiles per graph (25x16 = 400 exactly)
#define ATS 420           // A-tile LDS stride (floats)
#define HTS 72            // h-tile LDS stride (halves)
#define MTSZ 25600        // per-graph M^T elems (64*400)

// wf buffer layout (halves)
#define W1F_OFF 0
#define W1F_N   (13*4*64*8)          // 26624
#define W2F_OFF (W1F_OFF + W1F_N)    // 26624
#define W2F_N   (2*4*64*8)           // 4096
#define W3F_OFF (W2F_OFF + W2F_N)    // 30720
#define WCF_OFF (W3F_OFF + W2F_N)    // 34816
#define WCF_N   (800*4*64*8)         // 1638400
#define WF_TOT  (WCF_OFF + WCF_N)    // 1673216

typedef __attribute__((ext_vector_type(8))) _Float16 h8;
typedef __attribute__((ext_vector_type(4))) float f32x4;

static __device__ __forceinline__ unsigned packh2(float a, float b) {
  unsigned short ua = __builtin_bit_cast(unsigned short, (_Float16)a);
  unsigned short ub = __builtin_bit_cast(unsigned short, (_Float16)b);
  return (unsigned)ua | ((unsigned)ub << 16);
}

static __device__ __forceinline__ h8 cvt8(float4 a, float4 b) {
  h8 r;
  r[0] = (_Float16)a.x; r[1] = (_Float16)a.y; r[2] = (_Float16)a.z; r[3] = (_Float16)a.w;
  r[4] = (_Float16)b.x; r[5] = (_Float16)b.y; r[6] = (_Float16)b.z; r[7] = (_Float16)b.w;
  return r;
}

// ---------------- kPack: all weights -> fp16 B-frag order; zero gbuf --------
__global__ __launch_bounds__(256) void kPack(
    const float* __restrict__ W1, const float* __restrict__ W2,
    const float* __restrict__ W3, const float* __restrict__ Wc,
    _Float16* __restrict__ wf, float* __restrict__ gbuf)
{
  int idx = blockIdx.x*256 + threadIdx.x;
  if (idx < G*H) gbuf[idx] = 0.f;
  if (idx >= WF_TOT) return;
  if (idx < W2F_OFF) {                       // W1: [ks 13][nt 4][lane][j]
    int i = idx;
    int j = i & 7, ln = (i >> 3) & 63, nt = (i >> 9) & 3, ks = i >> 11;
    int k = ks*32 + (ln >> 4)*8 + j, col = nt*16 + (ln & 15);
    wf[idx] = (k < FIN) ? (_Float16)W1[k*H + col] : (_Float16)0.f;
  } else if (idx < W3F_OFF) {                // W2: [ks 2][nt 4][lane][j]
    int i = idx - W2F_OFF;
    int j = i & 7, ln = (i >> 3) & 63, nt = (i >> 9) & 3, ks = i >> 11;
    wf[idx] = (_Float16)W2[(ks*32 + (ln >> 4)*8 + j)*H + nt*16 + (ln & 15)];
  } else if (idx < WCF_OFF) {                // W3
    int i = idx - W3F_OFF;
    int j = i & 7, ln = (i >> 3) & 63, nt = (i >> 9) & 3, ks = i >> 11;
    wf[idx] = (_Float16)W3[(ks*32 + (ln >> 4)*8 + j)*H + nt*16 + (ln & 15)];
  } else {                                   // Wc with k' = feat*400 + node perm
    int i = idx - WCF_OFF;
    int j = i & 7, ln = (i >> 3) & 63, nt = (i >> 9) & 3, kt = i >> 11;
    int kp = kt*32 + (ln >> 4)*8 + j;        // 0..25599
    int node = kp % 400, feat = kp / 400;
    int col = nt*16 + (ln & 15);
    wf[idx] = (_Float16)Wc[((size_t)node*64 + feat)*64 + col];
  }
}

// ---------------- kNorm: 1024 thr; degree + entries bucketed by 16-row tile --
__global__ __launch_bounds__(1024) void kNorm(
    const int* __restrict__ ei, const float* __restrict__ ew,
    uint2* __restrict__ ent, uint32_t* __restrict__ boff)
{
  __shared__ float deg[NPG];
  __shared__ float dv[NPG];
  __shared__ uint32_t bcnt[32], bpos[32];
  const int g = blockIdx.x, tid = threadIdx.x;
  const int ebase = g*EPG, nbase = g*NPG;
  const int* rowp = ei;          // sources
  const int* colp = ei + EE;     // targets
  if (tid < NTILE) bcnt[tid] = 0u;
  for (int v = tid; v < NPG; v += 1024) deg[v] = 1.0f;   // self-loop weight
  __syncthreads();
  for (int e = tid; e < EPG; e += 1024) {
    int c = colp[ebase+e] - nbase;
    atomicAdd(&deg[c], ew[ebase+e]);
    atomicAdd(&bcnt[c >> 4], 1u);
  }
  __syncthreads();
  for (int v = tid; v < NPG; v += 1024) dv[v] = rsqrtf(deg[v]);
  if (tid == 0) {
    uint32_t s = 0;
    #pragma unroll
    for (int t = 0; t < NTILE; ++t) {
      uint32_t c = bcnt[t] + 16u;              // + 16 self loops per tile
      bcnt[t] = s; bpos[t] = s; s += c;
    }
  }
  __syncthreads();
  if (tid < NTILE) boff[g*32 + tid] = bcnt[tid];
  if (tid == NTILE) boff[g*32 + NTILE] = (uint32_t)CPG;
  uint2* eb = ent + (size_t)g*CPG;
  for (int e = tid; e < EPG; e += 1024) {
    int src = rowp[ebase+e] - nbase;
    int dst = colp[ebase+e] - nbase;
    float nm = dv[src] * ew[ebase+e] * dv[dst];
    uint32_t p = atomicAdd(&bpos[dst >> 4], 1u);
    eb[p] = make_uint2(((unsigned)dst << 16) | (unsigned)src, __float_as_uint(nm));
  }
  for (int v = tid; v < NPG; v += 1024) {
    uint32_t p = atomicAdd(&bpos[v >> 4], 1u);
    eb[p] = make_uint2(((unsigned)v << 16) | (unsigned)v, __float_as_uint(dv[v]*dv[v]));
  }
}

// ---------------- kM1: MT1 = (x @ W1)^T  per-graph [feat][node], fp16 -------
// ks-OUTER loop: af loaded once per ks and immediately consumed by 4 MFMAs
// (nt-outer form made the compiler re-load x 4x; r9 kFront VGPR=60 evidence).
__global__ __launch_bounds__(256, 4) void kM1(
    const float* __restrict__ x, const _Float16* __restrict__ wf,
    _Float16* __restrict__ mt1)
{
  __shared__ _Float16 sh[64*HTS];            // 9216 B out-stage
  const int tid = threadIdx.x, lane = tid & 63, wave = tid >> 6;
  const int l15 = lane & 15, kgrp = lane >> 4;
  const int g = blockIdx.y, b = blockIdx.x;  // b < 7, nodes b*64..b*64+63
  const int node_l = b*64 + wave*16 + l15;
  const int arow = (node_l < NPG) ? node_l : NPG-1;
  const float* xp = x + ((size_t)g*NPG + arow)*FIN;

  f32x4 acc[4] = {{0,0,0,0},{0,0,0,0},{0,0,0,0},{0,0,0,0}};
  for (int ks = 0; ks < 13; ++ks) {
    const int kb = ks*32 + kgrp*8;
    h8 af;
    if (kb + 8 <= FIN) {
      float4 a0 = *(const float4*)(xp + kb);
      float4 a1 = *(const float4*)(xp + kb + 4);
      af = cvt8(a0, a1);
    } else {
      h8 z;
      #pragma unroll
      for (int j = 0; j < 8; ++j) z[j] = (_Float16)0.f;
      af = z;
    }
    #pragma unroll
    for (int nt = 0; nt < 4; ++nt) {
      h8 bf = *(const h8*)&wf[W1F_OFF + (((size_t)ks*4 + nt)*64 + lane)*8];
      acc[nt] = __builtin_amdgcn_mfma_f32_16x16x32_f16(af, bf, acc[nt], 0, 0, 0);
    }
  }
  // stage [node_local][feat]
  #pragma unroll
  for (int nt = 0; nt < 4; ++nt) {
    int feat = nt*16 + l15;
    #pragma unroll
    for (int r = 0; r < 4; ++r)
      sh[(wave*16 + kgrp*4 + r)*HTS + feat] = (_Float16)acc[nt][r];
  }
  __syncthreads();
  // transposed coalesced store: MT1[g][feat][b*64 + 0..63]
  const unsigned short* shu = (const unsigned short*)sh;
  for (int i = tid; i < 64*16; i += 256) {
    int feat = i >> 4, seg = i & 15;
    int nl = seg*4, gn = b*64 + nl;
    if (gn < NPG) {
      uint2 u;
      u.x = (unsigned)shu[(nl+0)*HTS + feat] | ((unsigned)shu[(nl+1)*HTS + feat] << 16);
      u.y = (unsigned)shu[(nl+2)*HTS + feat] | ((unsigned)shu[(nl+3)*HTS + feat] << 16);
      *(uint2*)&mt1[(size_t)g*MTSZ + feat*400 + gn] = u;
    }
  }
}

// ---------------- kAgg<WMUL>: one 16-row dst tile: scatter + agg MFMA --------
// WMUL=1: + bias + relu + fused next-layer GEMM -> MT_out.  WMUL=0: + bias -> MT out.
template<int WMUL>
__global__ __launch_bounds__(256, 4) void kAgg(
    const _Float16* __restrict__ mtin, const _Float16* __restrict__ wfn,
    const float* __restrict__ bias,
    const uint2* __restrict__ ent, const uint32_t* __restrict__ boff,
    _Float16* __restrict__ out)
{
  extern __shared__ char smem[];
  float* sAT = (float*)smem;                     // 16*420*4 = 26880 B
  _Float16* sh = (_Float16*)(smem + 16*ATS*4);   // 16*72*2  = 2304 B
  const int tid = threadIdx.x, lane = tid & 63;
  const int l15 = lane & 15, kgrp = lane >> 4;
  const int bid = blockIdx.x;
  const int g = bid & 255, t = bid >> 8;         // same-graph blocks share XCD
  const int t0 = t*16;
  const int nt = tid >> 6;                       // wave = output col quarter
  const uint2* eb = ent + (size_t)g*CPG;
  const uint32_t s0 = boff[g*32 + t], s1 = boff[g*32 + t + 1];

  // global prefetches (independent; overlap with zeroing)
  h8 BF[13];
  const _Float16* mrow = mtin + (size_t)g*MTSZ + (nt*16 + l15)*400;
  #pragma unroll
  for (int ks = 0; ks < 13; ++ks)
    BF[ks] = *(const h8*)(mrow + ks*32 + kgrp*8);
  const float bv = bias[nt*16 + l15];
  h8 WF2[2];
  if (WMUL) {
    WF2[0] = *(const h8*)&wfn[((size_t)(0*4 + nt)*64 + lane)*8];
    WF2[1] = *(const h8*)&wfn[((size_t)(1*4 + nt)*64 + lane)*8];
  }
  const uint32_t e0 = s0 + tid;
  uint2 E0 = make_uint2(0,0), E1 = make_uint2(0,0), E2 = make_uint2(0,0);
  if (e0       < s1) E0 = eb[e0];
  if (e0 + 256 < s1) E1 = eb[e0 + 256];
  if (e0 + 512 < s1) E2 = eb[e0 + 512];

  // zero A-tile
  { float4* p = (float4*)sAT;
    for (int i = tid; i < 16*ATS/4; i += 256) p[i] = make_float4(0,0,0,0); }
  __syncthreads();

  // scatter
  if (e0       < s1) atomicAdd(&sAT[((int)(E0.x >> 16) - t0)*ATS + (int)(E0.x & 0xffffu)], __uint_as_float(E0.y));
  if (e0 + 256 < s1) atomicAdd(&sAT[((int)(E1.x >> 16) - t0)*ATS + (int)(E1.x & 0xffffu)], __uint_as_float(E1.y));
  if (e0 + 512 < s1) atomicAdd(&sAT[((int)(E2.x >> 16) - t0)*ATS + (int)(E2.x & 0xffffu)], __uint_as_float(E2.y));
  for (uint32_t e = e0 + 768; e < s1; e += 256) {      // overflow guard
    uint2 E = eb[e];
    atomicAdd(&sAT[((int)(E.x >> 16) - t0)*ATS + (int)(E.x & 0xffffu)], __uint_as_float(E.y));
  }
  __syncthreads();

  // agg MFMA: 16 nodes x 16 cols per wave
  f32x4 acc = {0,0,0,0};
  const float* ap = &sAT[l15*ATS];
  #pragma unroll
  for (int ks = 0; ks < 13; ++ks) {
    int kb = ks*32 + kgrp*8;
    float4 a0 = *(const float4*)(ap + kb);
    float4 a1 = *(const float4*)(ap + kb + 4);
    acc = __builtin_amdgcn_mfma_f32_16x16x32_f16(cvt8(a0, a1), BF[ks], acc, 0, 0, 0);
  }

  const int node0 = t0 + kgrp*4;
  if (!WMUL) {
    // layer 3: bias only, store MT layout (= h3 transposed k' order)
    uint2 u;
    u.x = packh2(acc[0] + bv, acc[1] + bv);
    u.y = packh2(acc[2] + bv, acc[3] + bv);
    *(uint2*)&out[(size_t)g*MTSZ + (nt*16 + l15)*400 + node0] = u;
  } else {
    // bias + relu -> h-tile LDS
    #pragma unroll
    for (int r = 0; r < 4; ++r)
      sh[(kgrp*4 + r)*HTS + nt*16 + l15] = (_Float16)fmaxf(acc[r] + bv, 0.f);
    __syncthreads();
    // fused next-layer GEMM: M_out-tile = h_tile @ Wn
    f32x4 acc2 = {0,0,0,0};
    const _Float16* hp = &sh[l15*HTS];
    acc2 = __builtin_amdgcn_mfma_f32_16x16x32_f16(*(const h8*)(hp + kgrp*8),      WF2[0], acc2, 0, 0, 0);
    acc2 = __builtin_amdgcn_mfma_f32_16x16x32_f16(*(const h8*)(hp + 32 + kgrp*8), WF2[1], acc2, 0, 0, 0);
    uint2 u;
    u.x = packh2(acc2[0], acc2[1]);
    u.y = packh2(acc2[2], acc2[3]);
    *(uint2*)&out[(size_t)g*MTSZ + (nt*16 + l15)*400 + node0] = u;
  }
}

// ---------------- kRead: gbuf += h3T[16 graphs] @ Wc' (split-K, MFMA) --------
__global__ __launch_bounds__(256) void kRead(
    const _Float16* __restrict__ h3, const _Float16* __restrict__ wfc,
    float* __restrict__ gbuf)
{
  const int tid = threadIdx.x, lane = tid & 63, nt = tid >> 6;
  const int l15 = lane & 15, kgrp = lane >> 4;
  const int rt = blockIdx.x & 15, kc = blockIdx.x >> 4;   // 16 row-tiles x 32 k-chunks
  f32x4 acc = {0,0,0,0};
  const _Float16* hp = h3 + (size_t)(rt*16 + l15)*MTSZ;
  for (int ks = 0; ks < 25; ++ks) {
    int kt = kc*25 + ks;
    h8 af = *(const h8*)(hp + kt*32 + kgrp*8);
    h8 bf = *(const h8*)(wfc + (((size_t)kt*4 + nt)*64 + lane)*8);
    acc = __builtin_amdgcn_mfma_f32_16x16x32_f16(af, bf, acc, 0, 0, 0);
  }
  #pragma unroll
  for (int r = 0; r < 4; ++r)
    atomicAdd(&gbuf[(size_t)(rt*16 + kgrp*4 + r)*H + nt*16 + l15], acc[r]);
}

// ---------------- k6: out = (g + bc) @ Wl + bl ----------------
__global__ __launch_bounds__(64) void k6_final(
    const float* __restrict__ gbuf, const float* __restrict__ bc,
    const float* __restrict__ Wl, const float* __restrict__ bl,
    float* __restrict__ out)
{
  int t = blockIdx.x*64 + threadIdx.x;   // 512 = 256 graphs * 2 outputs
  int gr = t >> 1, c = t & 1;
  float acc = bl[c];
  for (int f = 0; f < H; ++f)
    acc += (gbuf[gr*H + f] + bc[f]) * Wl[f*2 + c];
  out[gr*2 + c] = acc;
}

extern "C" void kernel_launch(void* const* d_in, const int* in_sizes, int n_in,
                              void* d_out, int out_size, void* d_ws, size_t ws_size,
                              hipStream_t stream)
{
  const float* x  = (const float*)d_in[0];
  const int*   ei = (const int*)d_in[1];
  const float* ew = (const float*)d_in[2];
  const float* W1 = (const float*)d_in[3];
  const float* b1 = (const float*)d_in[4];
  const float* W2 = (const float*)d_in[5];
  const float* b2 = (const float*)d_in[6];
  const float* W3 = (const float*)d_in[7];
  const float* b3 = (const float*)d_in[8];
  const float* Wc = (const float*)d_in[9];
  const float* bc = (const float*)d_in[10];
  const float* Wl = (const float*)d_in[11];
  const float* bl = (const float*)d_in[12];
  float* out = (float*)d_out;
  (void)ws_size;

  char* ws = (char*)d_ws;
  size_t o = 0;
  uint2*     ent  = (uint2*)(ws + o);     o += (size_t)G*CPG*8;        // 27.0 MB
  uint32_t*  boff = (uint32_t*)(ws + o);  o += (size_t)G*32*4;         // 32 KB
  _Float16*  mtA  = (_Float16*)(ws + o);  o += (size_t)G*MTSZ*2 + 256; // 13.1 MB
  _Float16*  mtB  = (_Float16*)(ws + o);  o += (size_t)G*MTSZ*2 + 256; // 13.1 MB
  _Float16*  wf   = (_Float16*)(ws + o);  o += (size_t)WF_TOT*2;       // 3.3 MB
  float*     gbuf = (float*)(ws + o);     o += (size_t)G*H*4;          // 64 KB

  kPack<<<(WF_TOT+255)/256, 256, 0, stream>>>(W1, W2, W3, Wc, wf, gbuf);
  kNorm<<<G, 1024, 0, stream>>>(ei, ew, ent, boff);
  kM1<<<dim3(7, G), 256, 0, stream>>>(x, wf, mtA);
  const int aggLds = 16*ATS*4 + 16*HTS*2;   // 26880 + 2304 = 29184 B
  kAgg<1><<<NTILE*G, 256, aggLds, stream>>>(mtA, wf + W2F_OFF, b1, ent, boff, mtB);
  kAgg<1><<<NTILE*G, 256, aggLds, stream>>>(mtB, wf + W3F_OFF, b2, ent, boff, mtA);
  kAgg<0><<<NTILE*G, 256, aggLds, stream>>>(mtA, wf, b3, ent, boff, mtB);
  kRead<<<512, 256, 0, stream>>>(mtB, wf + WCF_OFF, gbuf);
  k6_final<<<8, 64, 0, stream>>>(gbuf, bc, Wl, bl, out);
}

// Round 12
// 265.638 us; speedup vs baseline: 1.1543x; 1.0078x over previous
//
#include <hip/hip_runtime.h>
#include <hip/hip_bf16.h>
#include <stdint.h>

#define G 256
#define NPG 400
#define DEG 32
#define FIN 400
#define H 64
#define NN (G*NPG)        // 102400
#define EE (G*NPG*DEG)    // 3276800
#define EPG (NPG*DEG)     // 12800 edges per graph
#define CPG (EPG+NPG)     // 13200 entries per graph (edges + self loops)
#define NTILE 25          // 16-row dst tiles per graph (25x16 = 400 exactly)
#define ATS 420           // A-tile LDS stride (floats)
#define HTS 72            // h-tile LDS stride (halves)
#define MTF 26624         // per-graph M fragment-order elems: 4nt*13ks*64lane*8j

// wf buffer layout (halves)
#define W1F_OFF 0
#define W1F_N   (13*4*64*8)          // 26624
#define W2F_OFF (W1F_OFF + W1F_N)    // 26624
#define W2F_N   (2*4*64*8)           // 4096
#define W3F_OFF (W2F_OFF + W2F_N)    // 30720
#define WCF_OFF (W3F_OFF + W2F_N)    // 34816
#define WCF_N   (832*4*64*8)         // 1703936  (K' = 26624 = 832 kt-chunks)
#define WF_TOT  (WCF_OFF + WCF_N)    // 1738752

typedef __attribute__((ext_vector_type(8))) _Float16 h8;
typedef __attribute__((ext_vector_type(4))) float f32x4;

static __device__ __forceinline__ unsigned packh2(float a, float b) {
  unsigned short ua = __builtin_bit_cast(unsigned short, (_Float16)a);
  unsigned short ub = __builtin_bit_cast(unsigned short, (_Float16)b);
  return (unsigned)ua | ((unsigned)ub << 16);
}

static __device__ __forceinline__ h8 cvt8(float4 a, float4 b) {
  h8 r;
  r[0] = (_Float16)a.x; r[1] = (_Float16)a.y; r[2] = (_Float16)a.z; r[3] = (_Float16)a.w;
  r[4] = (_Float16)b.x; r[5] = (_Float16)b.y; r[6] = (_Float16)b.z; r[7] = (_Float16)b.w;
  return r;
}

// ---------------- kPack: all weights -> fp16 B-frag order ----------
// Wc uses k' = mtF flat order permutation; node>=400 slots get 0.
__global__ __launch_bounds__(256) void kPack(
    const float* __restrict__ W1, const float* __restrict__ W2,
    const float* __restrict__ W3, const float* __restrict__ Wc,
    _Float16* __restrict__ wf)
{
  int idx = blockIdx.x*256 + threadIdx.x;
  if (idx >= WF_TOT) return;
  if (idx < W2F_OFF) {                       // W1: [ks 13][nt 4][lane][j]
    int i = idx;
    int j = i & 7, ln = (i >> 3) & 63, nt = (i >> 9) & 3, ks = i >> 11;
    int k = ks*32 + (ln >> 4)*8 + j, col = nt*16 + (ln & 15);
    wf[idx] = (k < FIN) ? (_Float16)W1[k*H + col] : (_Float16)0.f;
  } else if (idx < W3F_OFF) {                // W2: [ks 2][nt 4][lane][j]
    int i = idx - W2F_OFF;
    int j = i & 7, ln = (i >> 3) & 63, nt = (i >> 9) & 3, ks = i >> 11;
    wf[idx] = (_Float16)W2[(ks*32 + (ln >> 4)*8 + j)*H + nt*16 + (ln & 15)];
  } else if (idx < WCF_OFF) {                // W3
    int i = idx - W3F_OFF;
    int j = i & 7, ln = (i >> 3) & 63, nt = (i >> 9) & 3, ks = i >> 11;
    wf[idx] = (_Float16)W3[(ks*32 + (ln >> 4)*8 + j)*H + nt*16 + (ln & 15)];
  } else {                                   // Wc, k' = mtF flat index
    int i = idx - WCF_OFF;
    int j = i & 7, ln = (i >> 3) & 63, ntc = (i >> 9) & 3, kt = i >> 11;
    int kp = kt*32 + (ln >> 4)*8 + j;        // 0..26623 (mtF flat)
    int nt_m = kp / 6656, rem = kp % 6656;   // 6656 = 13*512
    int ks_m = rem >> 9, rem2 = rem & 511;
    int lane_m = rem2 >> 3, j_m = rem2 & 7;
    int node = ks_m*32 + (lane_m >> 4)*8 + j_m;
    int feat = nt_m*16 + (lane_m & 15);
    int col = ntc*16 + (ln & 15);
    wf[idx] = (node < NPG) ? (_Float16)Wc[((size_t)node*64 + feat)*64 + col]
                           : (_Float16)0.f;
  }
}

// ---------------- kNorm: 1024 thr; degree + entries bucketed by 16-row tile --
__global__ __launch_bounds__(1024) void kNorm(
    const int* __restrict__ ei, const float* __restrict__ ew,
    uint2* __restrict__ ent, uint32_t* __restrict__ boff)
{
  __shared__ float deg[NPG];
  __shared__ float dv[NPG];
  __shared__ uint32_t bcnt[32], bpos[32];
  const int g = blockIdx.x, tid = threadIdx.x;
  const int ebase = g*EPG, nbase = g*NPG;
  const int* rowp = ei;          // sources
  const int* colp = ei + EE;     // targets
  if (tid < NTILE) bcnt[tid] = 0u;
  for (int v = tid; v < NPG; v += 1024) deg[v] = 1.0f;   // self-loop weight
  __syncthreads();
  for (int e = tid; e < EPG; e += 1024) {
    int c = colp[ebase+e] - nbase;
    atomicAdd(&deg[c], ew[ebase+e]);
    atomicAdd(&bcnt[c >> 4], 1u);
  }
  __syncthreads();
  for (int v = tid; v < NPG; v += 1024) dv[v] = rsqrtf(deg[v]);
  if (tid == 0) {
    uint32_t s = 0;
    #pragma unroll
    for (int t = 0; t < NTILE; ++t) {
      uint32_t c = bcnt[t] + 16u;              // + 16 self loops per tile
      bcnt[t] = s; bpos[t] = s; s += c;
    }
  }
  __syncthreads();
  if (tid < NTILE) boff[g*32 + tid] = bcnt[tid];
  if (tid == NTILE) boff[g*32 + NTILE] = (uint32_t)CPG;
  uint2* eb = ent + (size_t)g*CPG;
  for (int e = tid; e < EPG; e += 1024) {
    int src = rowp[ebase+e] - nbase;
    int dst = colp[ebase+e] - nbase;
    float nm = dv[src] * ew[ebase+e] * dv[dst];
    uint32_t p = atomicAdd(&bpos[dst >> 4], 1u);
    eb[p] = make_uint2(((unsigned)dst << 16) | (unsigned)src, __float_as_uint(nm));
  }
  for (int v = tid; v < NPG; v += 1024) {
    uint32_t p = atomicAdd(&bpos[v >> 4], 1u);
    eb[p] = make_uint2(((unsigned)v << 16) | (unsigned)v, __float_as_uint(dv[v]*dv[v]));
  }
}

// ---------------- kM1: mtF1 = frag-order (x @ W1), fp16, no LDS -------------
__global__ __launch_bounds__(256, 8) void kM1(
    const float* __restrict__ x, const _Float16* __restrict__ wf,
    _Float16* __restrict__ mt1)
{
  const int tid = threadIdx.x, lane = tid & 63, wave = tid >> 6;
  const int l15 = lane & 15, kgrp = lane >> 4;
  const int g = blockIdx.y, b = blockIdx.x;  // b < 7, nodes b*64..b*64+63
  const int node_l = b*64 + wave*16 + l15;
  const int arow = (node_l < NPG) ? node_l : NPG-1;
  const float* xp = x + ((size_t)g*NPG + arow)*FIN;

  f32x4 acc[4] = {{0,0,0,0},{0,0,0,0},{0,0,0,0},{0,0,0,0}};
  for (int ks = 0; ks < 13; ++ks) {
    const int kb = ks*32 + kgrp*8;
    h8 af;
    if (kb + 8 <= FIN) {
      float4 a0 = *(const float4*)(xp + kb);
      float4 a1 = *(const float4*)(xp + kb + 4);
      af = cvt8(a0, a1);
    } else {
      h8 z;
      #pragma unroll
      for (int j = 0; j < 8; ++j) z[j] = (_Float16)0.f;
      af = z;
    }
    #pragma unroll
    for (int nt = 0; nt < 4; ++nt) {
      h8 bf = *(const h8*)&wf[W1F_OFF + (((size_t)ks*4 + nt)*64 + lane)*8];
      acc[nt] = __builtin_amdgcn_mfma_f32_16x16x32_f16(af, bf, acc[nt], 0, 0, 0);
    }
  }
  // direct fragment-order write: D row = kgrp*4+r -> node; col = nt*16+l15
  const int nd0 = b*64 + wave*16 + kgrp*4;
  if (nd0 < NPG) {
    const int ksw = nd0 >> 5, lh = (nd0 >> 3) & 3, jb = nd0 & 7;
    _Float16* mb = mt1 + (size_t)g*MTF;
    #pragma unroll
    for (int nt = 0; nt < 4; ++nt) {
      uint2 u;
      u.x = packh2(acc[nt][0], acc[nt][1]);
      u.y = packh2(acc[nt][2], acc[nt][3]);
      *(uint2*)&mb[(((size_t)nt*13 + ksw)*64 + lh*16 + l15)*8 + jb] = u;
    }
  }
}

// ---------------- kAgg<WMUL>: one 16-row dst tile: scatter + agg MFMA --------
// Input/output M in fragment order. WMUL=1: +bias+relu+next-layer GEMM.
template<int WMUL>
__global__ __launch_bounds__(256, 4) void kAgg(
    const _Float16* __restrict__ mtin, const _Float16* __restrict__ wfn,
    const float* __restrict__ bias,
    const uint2* __restrict__ ent, const uint32_t* __restrict__ boff,
    _Float16* __restrict__ out)
{
  extern __shared__ char smem[];
  float* sAT = (float*)smem;                     // 16*420*4 = 26880 B
  _Float16* sh = (_Float16*)(smem + 16*ATS*4);   // 16*72*2  = 2304 B
  const int tid = threadIdx.x, lane = tid & 63;
  const int l15 = lane & 15, kgrp = lane >> 4;
  const int bid = blockIdx.x;
  const int g = bid & 255, t = bid >> 8;         // same-graph blocks share XCD
  const int t0 = t*16;
  const int nt = tid >> 6;                       // wave = output col quarter
  const uint2* eb = ent + (size_t)g*CPG;
  const uint32_t s0 = boff[g*32 + t], s1 = boff[g*32 + t + 1];

  // coalesced BF prefetch: 13 x 1KB wave loads (frag-order mt)
  h8 BF[13];
  const _Float16* mrow = mtin + (size_t)g*MTF + (size_t)nt*13*512 + lane*8;
  #pragma unroll
  for (int ks = 0; ks < 13; ++ks)
    BF[ks] = *(const h8*)(mrow + ks*512);
  const float bv = bias[nt*16 + l15];
  h8 WF2[2];
  if (WMUL) {
    WF2[0] = *(const h8*)&wfn[((size_t)(0*4 + nt)*64 + lane)*8];
    WF2[1] = *(const h8*)&wfn[((size_t)(1*4 + nt)*64 + lane)*8];
  }
  const uint32_t e0 = s0 + tid;
  uint2 E0 = make_uint2(0,0), E1 = make_uint2(0,0), E2 = make_uint2(0,0);
  if (e0       < s1) E0 = eb[e0];
  if (e0 + 256 < s1) E1 = eb[e0 + 256];
  if (e0 + 512 < s1) E2 = eb[e0 + 512];

  // zero A-tile
  { float4* p = (float4*)sAT;
    for (int i = tid; i < 16*ATS/4; i += 256) p[i] = make_float4(0,0,0,0); }
  __syncthreads();

  // scatter
  if (e0       < s1) atomicAdd(&sAT[((int)(E0.x >> 16) - t0)*ATS + (int)(E0.x & 0xffffu)], __uint_as_float(E0.y));
  if (e0 + 256 < s1) atomicAdd(&sAT[((int)(E1.x >> 16) - t0)*ATS + (int)(E1.x & 0xffffu)], __uint_as_float(E1.y));
  if (e0 + 512 < s1) atomicAdd(&sAT[((int)(E2.x >> 16) - t0)*ATS + (int)(E2.x & 0xffffu)], __uint_as_float(E2.y));
  for (uint32_t e = e0 + 768; e < s1; e += 256) {      // overflow guard
    uint2 E = eb[e];
    atomicAdd(&sAT[((int)(E.x >> 16) - t0)*ATS + (int)(E.x & 0xffffu)], __uint_as_float(E.y));
  }
  __syncthreads();

  // agg MFMA: 16 nodes x 16 cols per wave
  f32x4 acc = {0,0,0,0};
  const float* ap = &sAT[l15*ATS];
  #pragma unroll
  for (int ks = 0; ks < 13; ++ks) {
    int kb = ks*32 + kgrp*8;
    float4 a0 = *(const float4*)(ap + kb);
    float4 a1 = *(const float4*)(ap + kb + 4);
    acc = __builtin_amdgcn_mfma_f32_16x16x32_f16(cvt8(a0, a1), BF[ks], acc, 0, 0, 0);
  }

  // fragment-order write coords for output node block
  const int nd0 = t0 + kgrp*4;                 // < 400 always
  const int ksw = nd0 >> 5, lh = (nd0 >> 3) & 3, jb = nd0 & 7;
  _Float16* ob = out + (size_t)g*MTF;

  if (!WMUL) {
    uint2 u;
    u.x = packh2(acc[0] + bv, acc[1] + bv);
    u.y = packh2(acc[2] + bv, acc[3] + bv);
    *(uint2*)&ob[(((size_t)nt*13 + ksw)*64 + lh*16 + l15)*8 + jb] = u;
  } else {
    // bias + relu -> h-tile LDS
    #pragma unroll
    for (int r = 0; r < 4; ++r)
      sh[(kgrp*4 + r)*HTS + nt*16 + l15] = (_Float16)fmaxf(acc[r] + bv, 0.f);
    __syncthreads();
    // fused next-layer GEMM: M_out-tile = h_tile @ Wn
    f32x4 acc2 = {0,0,0,0};
    const _Float16* hp = &sh[l15*HTS];
    acc2 = __builtin_amdgcn_mfma_f32_16x16x32_f16(*(const h8*)(hp + kgrp*8),      WF2[0], acc2, 0, 0, 0);
    acc2 = __builtin_amdgcn_mfma_f32_16x16x32_f16(*(const h8*)(hp + 32 + kgrp*8), WF2[1], acc2, 0, 0, 0);
    uint2 u;
    u.x = packh2(acc2[0], acc2[1]);
    u.y = packh2(acc2[2], acc2[3]);
    *(uint2*)&ob[(((size_t)nt*13 + ksw)*64 + lh*16 + l15)*8 + jb] = u;
  }
}

// ---------------- kRead: gpart[kc] = h3F[16 graphs] @ Wc' chunk (no atomics) -
__global__ __launch_bounds__(256) void kRead(
    const _Float16* __restrict__ h3, const _Float16* __restrict__ wfc,
    float* __restrict__ gpart)
{
  const int tid = threadIdx.x, lane = tid & 63, nt = tid >> 6;
  const int l15 = lane & 15, kgrp = lane >> 4;
  const int rt = blockIdx.x & 15, kc = blockIdx.x >> 4;   // 16 row-tiles x 32 k-chunks
  f32x4 acc = {0,0,0,0};
  const _Float16* hp = h3 + (size_t)(rt*16 + l15)*MTF;
  for (int ks = 0; ks < 26; ++ks) {
    int kt = kc*26 + ks;                                  // < 832
    h8 af = *(const h8*)(hp + kt*32 + kgrp*8);
    h8 bf = *(const h8*)(wfc + (((size_t)kt*4 + nt)*64 + lane)*8);
    acc = __builtin_amdgcn_mfma_f32_16x16x32_f16(af, bf, acc, 0, 0, 0);
  }
  #pragma unroll
  for (int r = 0; r < 4; ++r)
    gpart[((size_t)(kc*16 + rt)*16 + kgrp*4 + r)*64 + nt*16 + l15] = acc[r];
}

// ---------------- k6: out[g] = (sum_kc gpart + bc) @ Wl + bl -----------------
__global__ __launch_bounds__(64) void k6_final(
    const float* __restrict__ gpart, const float* __restrict__ bc,
    const float* __restrict__ Wl, const float* __restrict__ bl,
    float* __restrict__ out)
{
  const int g = blockIdx.x, f = threadIdx.x;   // 256 blocks x 64 threads
  float s = bc[f];
  #pragma unroll 4
  for (int kc = 0; kc < 32; ++kc)
    s += gpart[((size_t)(kc*16 + (g >> 4))*16 + (g & 15))*64 + f];
  float p0 = s * Wl[f*2 + 0];
  float p1 = s * Wl[f*2 + 1];
  #pragma unroll
  for (int d = 1; d < 64; d <<= 1) {
    p0 += __shfl_xor(p0, d);
    p1 += __shfl_xor(p1, d);
  }
  if (f == 0) {
    out[g*2 + 0] = p0 + bl[0];
    out[g*2 + 1] = p1 + bl[1];
  }
}

extern "C" void kernel_launch(void* const* d_in, const int* in_sizes, int n_in,
                              void* d_out, int out_size, void* d_ws, size_t ws_size,
                              hipStream_t stream)
{
  const float* x  = (const float*)d_in[0];
  const int*   ei = (const int*)d_in[1];
  const float* ew = (const float*)d_in[2];
  const float* W1 = (const float*)d_in[3];
  const float* b1 = (const float*)d_in[4];
  const float* W2 = (const float*)d_in[5];
  const float* b2 = (const float*)d_in[6];
  const float* W3 = (const float*)d_in[7];
  const float* b3 = (const float*)d_in[8];
  const float* Wc = (const float*)d_in[9];
  const float* bc = (const float*)d_in[10];
  const float* Wl = (const float*)d_in[11];
  const float* bl = (const float*)d_in[12];
  float* out = (float*)d_out;
  (void)ws_size;

  char* ws = (char*)d_ws;
  size_t o = 0;
  uint2*     ent   = (uint2*)(ws + o);     o += (size_t)G*CPG*8;        // 27.0 MB
  uint32_t*  boff  = (uint32_t*)(ws + o);  o += (size_t)G*32*4;         // 32 KB
  _Float16*  mtA   = (_Float16*)(ws + o);  o += (size_t)G*MTF*2 + 256;  // 13.6 MB
  _Float16*  mtB   = (_Float16*)(ws + o);  o += (size_t)G*MTF*2 + 256;  // 13.6 MB
  _Float16*  wf    = (_Float16*)(ws + o);  o += (size_t)WF_TOT*2;       // 3.5 MB
  float*     gpart = (float*)(ws + o);     o += (size_t)32*G*H*4;       // 2 MB

  kPack<<<WF_TOT/256, 256, 0, stream>>>(W1, W2, W3, Wc, wf);
  kNorm<<<G, 1024, 0, stream>>>(ei, ew, ent, boff);
  kM1<<<dim3(7, G), 256, 0, stream>>>(x, wf, mtA);
  const int aggLds = 16*ATS*4 + 16*HTS*2;   // 26880 + 2304 = 29184 B
  kAgg<1><<<NTILE*G, 256, aggLds, stream>>>(mtA, wf + W2F_OFF, b1, ent, boff, mtB);
  kAgg<1><<<NTILE*G, 256, aggLds, stream>>>(mtB, wf + W3F_OFF, b2, ent, boff, mtA);
  kAgg<0><<<NTILE*G, 256, aggLds, stream>>>(mtA, wf, b3, ent, boff, mtB);
  kRead<<<512, 256, 0, stream>>>(mtB, wf + WCF_OFF, gpart);
  k6_final<<<G, 64, 0, stream>>>(gpart, bc, Wl, bl, out);
}